// Round 1
// baseline (2152.466 us; speedup 1.0000x reference)
//
#include <hip/hip_runtime.h>
#include <stdint.h>

#define SEQ   2048
#define NBATCH 64
#define IND   256
#define HIDN  256

using short8  = __attribute__((ext_vector_type(8))) short;
using floatx4 = __attribute__((ext_vector_type(4))) float;

__device__ __forceinline__ unsigned bf16r(float f) {
    unsigned u = __builtin_bit_cast(unsigned, f);
    return (u + 0x8000u) >> 16;   // round-half-up to bf16
}

__device__ __forceinline__ short8 pack8(floatx4 f0, floatx4 f1) {
    short8 s;
    s[0] = (short)bf16r(f0[0]); s[1] = (short)bf16r(f0[1]);
    s[2] = (short)bf16r(f0[2]); s[3] = (short)bf16r(f0[3]);
    s[4] = (short)bf16r(f1[0]); s[5] = (short)bf16r(f1[1]);
    s[6] = (short)bf16r(f1[2]); s[7] = (short)bf16r(f1[3]);
    return s;
}

// tanh(z) = 1 - 2/(1+e^{2z});  e^{2z} = exp2(z * 2/ln2).  NaN-safe at +-inf.
__device__ __forceinline__ float tanh_fast(float z) {
    float a = __builtin_amdgcn_exp2f(z * 2.8853900817779268f);
    return __builtin_fmaf(-2.0f, __builtin_amdgcn_rcpf(1.0f + a), 1.0f);
}

// ---------------------------------------------------------------------------
// Kernel 1: x_proj[s][b][n] = sum_i input[s][b][i]*W_ih[n][i] + b_ih[n] + b_hh[n]
// stored as bf16 bits (ushort). Grid: 2048 blocks x 256 thr; 64 M-rows/block.
// MFMA 16x16x32 bf16; B-frags (W_ih) in registers; A loaded direct from global.
// ---------------------------------------------------------------------------
__global__ __launch_bounds__(256, 2) void proj_kernel(
    const float* __restrict__ inp, const float* __restrict__ W_ih,
    const float* __restrict__ b_ih, const float* __restrict__ b_hh,
    unsigned short* __restrict__ xp)
{
    const int tid  = threadIdx.x;
    const int w    = tid >> 6;          // wave 0..3 -> n-quarter
    const int lane = tid & 63;
    const int c    = lane & 15;         // lane&15: A row (m) / B col (n) / D col
    const int q    = lane >> 4;         // quad: k = q*8+j, D rows = q*4+r
    const size_t R0 = (size_t)blockIdx.x * 64;

    // B-frags: B[k][n] = W_ih[n][k]  (W_ih is [HID][IN], row-major -> k contiguous)
    short8 bfr[4][8];
    float bias[4];
    #pragma unroll
    for (int tn = 0; tn < 4; ++tn) {
        const int n = 64 * w + 16 * tn + c;
        bias[tn] = b_ih[n] + b_hh[n];
        #pragma unroll
        for (int kk = 0; kk < 8; ++kk) {
            const float* p = W_ih + (size_t)n * 256 + kk * 32 + q * 8;
            bfr[tn][kk] = pack8(*(const floatx4*)p, *(const floatx4*)(p + 4));
        }
    }

    #pragma unroll
    for (int mt = 0; mt < 4; ++mt) {
        // A-frags: A[m=c][k=kk*32+q*8+j] direct from global
        short8 afr[8];
        const float* arow = inp + (R0 + 16 * mt + c) * 256;
        #pragma unroll
        for (int kk = 0; kk < 8; ++kk) {
            const float* p = arow + kk * 32 + q * 8;
            afr[kk] = pack8(*(const floatx4*)p, *(const floatx4*)(p + 4));
        }
        floatx4 acc[4];
        #pragma unroll
        for (int tn = 0; tn < 4; ++tn) {
            floatx4 a0; a0[0] = bias[tn]; a0[1] = bias[tn]; a0[2] = bias[tn]; a0[3] = bias[tn];
            acc[tn] = a0;
            #pragma unroll
            for (int kk = 0; kk < 8; ++kk)
                acc[tn] = __builtin_amdgcn_mfma_f32_16x16x32_bf16(afr[kk], bfr[tn][kk], acc[tn], 0, 0, 0);
        }
        // D layout: col = c (n), row = q*4+r (m)
        #pragma unroll
        for (int tn = 0; tn < 4; ++tn) {
            const unsigned col = 64 * w + 16 * tn + c;
            #pragma unroll
            for (int r = 0; r < 4; ++r) {
                const size_t row = R0 + 16 * mt + q * 4 + r;
                xp[row * 256 + col] = (unsigned short)bf16r(acc[tn][r]);
            }
        }
    }
}

// ---------------------------------------------------------------------------
// Kernel 2: the serial recurrence. 4 blocks x 16 batches, 4 waves/block,
// each wave owns a 64-wide hidden slice. W_hh resident in registers (bf16
// B-frags); h double-buffered in LDS as bf16, row stride 264 ushort (528 B,
// 2-way bank aliasing = free). Raw s_barrier (LDS-only drain) so the 2-step
// x_proj register prefetch and the output stores stay in flight.
// ---------------------------------------------------------------------------
__global__ __launch_bounds__(256, 1) void rnn_kernel(
    const float* __restrict__ W_hh,
    const unsigned short* __restrict__ xp,   // bf16 bits [SEQ][NBATCH][HIDN]
    float* __restrict__ out)                 // fp32 [SEQ*NBATCH][HIDN]
{
    __shared__ __align__(16) unsigned short hbuf[2][16 * 264];
    const int tid  = threadIdx.x;
    const int w    = tid >> 6, lane = tid & 63;
    const int c    = lane & 15, q = lane >> 4;
    const int B0   = blockIdx.x * 16;

    // B-frags: B[k][n] = W_hh[n][k]
    short8 bfr[4][8];
    #pragma unroll
    for (int tn = 0; tn < 4; ++tn) {
        const int n = 64 * w + 16 * tn + c;
        #pragma unroll
        for (int kk = 0; kk < 8; ++kk) {
            const float* p = W_hh + (size_t)n * 256 + kk * 32 + q * 8;
            bfr[tn][kk] = pack8(*(const floatx4*)p, *(const floatx4*)(p + 4));
        }
    }

    // h0 = 0
    for (int i = tid; i < 2 * 16 * 264; i += 256) (&hbuf[0][0])[i] = 0;
    __syncthreads();

    // per-lane flat offset into [t][b][n]: b = B0+q*4+r, n = 64w+16tn+c
    const unsigned lofs = (unsigned)(B0 + q * 4) * 256 + 64 * w + c;
    const unsigned short* xq = xp + lofs;
    float* oq = out + lofs;

    // 2-deep xp prefetch ring (vals indexed i = r*4+tn)
    unsigned xa[16], xb[16];
    #pragma unroll
    for (int i = 0; i < 16; ++i) {
        const int tn = i & 3, r = i >> 2;
        xa[i] = xq[r * 256 + tn * 16];           // t = 0
        xb[i] = xq[16384 + r * 256 + tn * 16];   // t = 1
    }

    auto step = [&](int t, int sel, unsigned* xv) {
        // A-frags from LDS: A[m=c][k=kk*32+q*8+j], row stride 264 ushort
        short8 afr[8];
        #pragma unroll
        for (int kk = 0; kk < 8; ++kk)
            afr[kk] = *(const short8*)&hbuf[sel][c * 264 + kk * 32 + q * 8];

        // acc init = x_proj (consume prefetched regs; bf16 -> f32 is <<16)
        floatx4 acc[4];
        #pragma unroll
        for (int tn = 0; tn < 4; ++tn) {
            floatx4 a0;
            a0[0] = __builtin_bit_cast(float, xv[0 * 4 + tn] << 16);
            a0[1] = __builtin_bit_cast(float, xv[1 * 4 + tn] << 16);
            a0[2] = __builtin_bit_cast(float, xv[2 * 4 + tn] << 16);
            a0[3] = __builtin_bit_cast(float, xv[3 * 4 + tn] << 16);
            acc[tn] = a0;
        }

        // prefetch x_proj for t+2 (clamped; last loads are dead but in-bounds)
        {
            const int tp = (t + 2 < SEQ) ? (t + 2) : (SEQ - 1);
            const unsigned short* p = xq + (size_t)tp * 16384;
            #pragma unroll
            for (int i = 0; i < 16; ++i) {
                const int tn = i & 3, r = i >> 2;
                xv[i] = p[r * 256 + tn * 16];
            }
        }

        #pragma unroll
        for (int tn = 0; tn < 4; ++tn) {
            #pragma unroll
            for (int kk = 0; kk < 8; ++kk)
                acc[tn] = __builtin_amdgcn_mfma_f32_16x16x32_bf16(afr[kk], bfr[tn][kk], acc[tn], 0, 0, 0);
        }

        // epilogue: tanh, store fp32 out, write bf16 h_new to other LDS buffer
        float* op = oq + (size_t)t * 16384;
        unsigned short* hw = &hbuf[sel ^ 1][0];
        #pragma unroll
        for (int tn = 0; tn < 4; ++tn) {
            #pragma unroll
            for (int r = 0; r < 4; ++r) {
                const float hn = tanh_fast(acc[tn][r]);
                op[r * 256 + tn * 16] = hn;
                hw[(q * 4 + r) * 264 + 64 * w + 16 * tn + c] = (unsigned short)bf16r(hn);
            }
        }
        // LDS-only barrier: do NOT drain vmcnt (keeps prefetch/stores in flight)
        __asm__ volatile("s_waitcnt lgkmcnt(0)\ns_barrier" ::: "memory");
    };

    for (int t = 0; t < SEQ; t += 2) {
        step(t, 0, xa);
        step(t + 1, 1, xb);
    }
}

extern "C" void kernel_launch(void* const* d_in, const int* in_sizes, int n_in,
                              void* d_out, int out_size, void* d_ws, size_t ws_size,
                              hipStream_t stream) {
    const float* input = (const float*)d_in[0];
    const float* W_ih  = (const float*)d_in[1];
    const float* W_hh  = (const float*)d_in[2];
    const float* b_ih  = (const float*)d_in[3];
    const float* b_hh  = (const float*)d_in[4];
    float* out = (float*)d_out;
    unsigned short* xp = (unsigned short*)d_ws;  // 2048*64*256 bf16 = 64 MiB

    proj_kernel<<<(SEQ * NBATCH) / 64, 256, 0, stream>>>(input, W_ih, b_ih, b_hh, xp);
    rnn_kernel<<<4, 256, 0, stream>>>(W_hh, xp, out);
}